// Round 2
// baseline (516.213 us; speedup 1.0000x reference)
//
#include <hip/hip_runtime.h>

typedef unsigned short u16;
typedef __attribute__((ext_vector_type(8))) _Float16 f16x8;
typedef __attribute__((ext_vector_type(4))) float f32x4;
typedef __attribute__((ext_vector_type(4))) int i32x4;
typedef __attribute__((ext_vector_type(4))) unsigned short us4;

__device__ __forceinline__ u16 f2h(float f) {
  _Float16 h = (_Float16)f;
  return __builtin_bit_cast(unsigned short, h);
}
__device__ __forceinline__ float sigm(float v) { return 1.0f / (1.0f + __expf(-v)); }
__device__ __forceinline__ float tanh_(float v) {
  float t = __expf(-2.0f * fabsf(v));
  float r = (1.0f - t) / (1.0f + t);
  return v >= 0.0f ? r : -r;
}

// async global->LDS DMA, 16 B per lane; LDS dest = wave-uniform base + lane*16
typedef const __attribute__((address_space(1))) unsigned int* gas_t;
typedef __attribute__((address_space(3))) unsigned int* las_t;
__device__ __forceinline__ void gl16(const u16* g, u16* l) {
  __builtin_amdgcn_global_load_lds((gas_t)g, (las_t)l, 16, 0, 0);
}

// ---------------------------------------------------------------------------
// prep_big:
//  blocks 0..2047   = [es 8][p 256]: scores partials. FIX this round: load all
//                     16 f32x4 of WQ into registers FIRST (launch_bounds(,4)
//                     -> VGPR cap 128, was 44) so 16 loads stay in flight ->
//                     HBM-BW-bound instead of latency-bound.
//  blocks 2048..3071 = [set 2][chgrp 32][chunk 16] weight swizzle, LDS-free,
//                     fragment-major output (conv4 A ds_read = linear lane*16).
// ---------------------------------------------------------------------------
__global__ __launch_bounds__(256, 4) void prep_big(
    const float* __restrict__ WQ, const float* __restrict__ WK,
    const float* __restrict__ txt, const float* __restrict__ WV,
    const float* __restrict__ Wsw, const float* __restrict__ Wsb,
    const float* __restrict__ wi, const float* __restrict__ wf,
    const float* __restrict__ wo, const float* __restrict__ wc,
    const float* __restrict__ ui, const float* __restrict__ uf,
    const float* __restrict__ uo, const float* __restrict__ uc,
    u16* __restrict__ dstW, u16* __restrict__ dstU,
    float* __restrict__ scores, float* __restrict__ sb) {
  __shared__ float red[4][8];
  __shared__ float red2[4];
  int tid = threadIdx.x;
  if (blockIdx.x < 2048) {
    int p = blockIdx.x & 255;
    int es = blockIdx.x >> 8;                    // e-slice 0..7
    int t4 = tid & 63, eg = tid >> 6;            // t = t4*4..+3, e-subgroup eg
    const f32x4* base = (const f32x4*)WQ + ((size_t)p * 512 + es * 64 + eg * 16) * 64 + t4;
    f32x4 va[16];                                // 16 independent 16B loads in flight
#pragma unroll
    for (int i = 0; i < 16; ++i) va[i] = base[i * 64];
    f32x4 wkq[4];
    const f32x4* wkp = (const f32x4*)(WK + es * 64 + eg * 16);
#pragma unroll
    for (int i = 0; i < 4; ++i) wkq[i] = wkp[i];
    f32x4 m4 = {0.f, 0.f, 0.f, 0.f};
#pragma unroll
    for (int i = 0; i < 4; ++i)
#pragma unroll
      for (int e = 0; e < 4; ++e) m4 += va[i * 4 + e] * wkq[i][e];
    // all 8 batches at once: ILP across the shuffle chains, single barrier
    float v[8];
    const f32x4* txp = (const f32x4*)txt;
#pragma unroll
    for (int b = 0; b < 8; ++b) {
      f32x4 tx = txp[b * 64 + t4];
      v[b] = m4[0] * tx[0] + m4[1] * tx[1] + m4[2] * tx[2] + m4[3] * tx[3];
    }
#pragma unroll
    for (int off = 32; off; off >>= 1)
#pragma unroll
      for (int b = 0; b < 8; ++b) v[b] += __shfl_down(v[b], off, 64);
    if (t4 == 0)
#pragma unroll
      for (int b = 0; b < 8; ++b) red[eg][b] = v[b];
    __syncthreads();
    if (tid < 8) {
      float sv = red[0][tid] + red[1][tid] + red[2][tid] + red[3][tid];
      atomicAdd(&scores[tid * 256 + p], sv * 0.044194173824159216f);
    }
    if (blockIdx.x == 0) {
      float vv = WV[tid] * Wsw[tid] + WV[tid + 256] * Wsw[tid + 256];
#pragma unroll
      for (int off = 32; off; off >>= 1) vv += __shfl_down(vv, off, 64);
      if (t4 == 0) red2[eg] = vv;
      __syncthreads();
      if (tid == 0) {
        sb[0] = red2[0] + red2[1] + red2[2] + red2[3];
        sb[1] = Wsb[0];
      }
    }
    return;
  }
  // ---- weight swizzle (LDS-free, fragment-major output) ----
  int sbid = blockIdx.x - 2048;                  // 0..1023
  int set = sbid >> 9;
  int chgrp = (sbid >> 4) & 31;
  int chunk = sbid & 15;
  int q = tid & 3, gch = tid >> 2;               // 4 threads per (gate,chrow)
  int gate = gch >> 4, chrow = gch & 15;
  int ch = chgrp * 16 + chrow;
  const float* s;
  if (set == 0) s = gate == 0 ? wi : gate == 1 ? wf : gate == 2 ? wo : wc;
  else          s = gate == 0 ? ui : gate == 1 ? uf : gate == 2 ? uo : uc;
  // this thread's 72 contiguous floats: [cl = q*8 .. q*8+7][k9 0..8]
  const f32x4* src = (const f32x4*)(s + (size_t)(ch * 512 + chunk * 32) * 9) + q * 18;
  f32x4 va[18];
#pragma unroll
  for (int i = 0; i < 18; ++i) va[i] = src[i];
  u16* dst = (set == 0 ? dstW : dstU) + (size_t)(chgrp * 16 + chunk) * 18432
             + (size_t)(gate * 64 + q * 16 + chrow) * 8;
#pragma unroll
  for (int k9 = 0; k9 < 9; ++k9) {
    i32x4 wv;
#pragma unroll
    for (int w = 0; w < 4; ++w) {
      int i0 = (2 * w) * 9 + k9, i1 = (2 * w + 1) * 9 + k9;
      unsigned lo = f2h(va[i0 >> 2][i0 & 3]);
      unsigned hi = f2h(va[i1 >> 2][i1 & 3]);
      wv[w] = (int)(lo | (hi << 16));
    }
    *(i32x4*)(dst + k9 * 2048) = wv;             // wave covers a full 1KB line set
  }
}

// ---------------------------------------------------------------------------
// prep_inputs: coef from scores (softmax over h per (b,w)); AM = coef*x,
// H0 = x, fp16 NHWC [b][p][ch].
// ---------------------------------------------------------------------------
__global__ void prep_inputs(const float* __restrict__ x, const float* __restrict__ scores,
                            const float* __restrict__ sb,
                            u16* __restrict__ AM, u16* __restrict__ H0) {
  __shared__ float sc[16];
  int idx = blockIdx.x * 256 + threadIdx.x;  // NHWC flat index
  int ch = idx & 511, p = (idx >> 9) & 255, b = idx >> 17;
  int w = p & 15, h = p >> 4;
  if (threadIdx.x < 16) sc[threadIdx.x] = scores[b * 256 + threadIdx.x * 16 + w];
  __syncthreads();
  float s = sb[0], b0 = sb[1];
  float mx = -1e30f;
#pragma unroll
  for (int hh = 0; hh < 16; ++hh) mx = fmaxf(mx, sc[hh]);
  float den = 0.f, my = 0.f;
#pragma unroll
  for (int hh = 0; hh < 16; ++hh) {
    float e = __expf(sc[hh] - mx);
    den += e;
    if (hh == h) my = e;
  }
  float coef = 1.0f + b0 + s * my / den;
  float xv = x[(size_t)(b * 512 + ch) * 256 + p];
  AM[idx] = f2h(coef * xv);
  H0[idx] = f2h(xv);
}

// ---------------------------------------------------------------------------
// Fused 4-gate 3x3 conv, implicit GEMM (fp16 MFMA 16x16x32, fp32 acc).
// RESTRUCTURED this round (T3-minimum 2-phase pipeline):
//  - Grid 256 = [b 8][chgrp 32], 512 threads (8 waves), N=256 = full image
//    per block -> total weight DMA halved (each weight chunk staged by 8
//    blocks instead of 16), all on the weight slice's home XCD (chgrp&7).
//  - FULL double-buffered LDS (A 2x36.9KB + B 2x20.7KB = 115KB, 1 block/CU):
//    stage(k+1) issued BEFORE compute(k); ONE __syncthreads per chunk whose
//    vmcnt(0) drain now overlaps 72 MFMAs/wave instead of stalling the block.
//  - A fragment-major (linear lane*16 ds_read, 0 conflicts); B XOR-swizzled
//    at the DMA's global source, undone at ds_read (2-way, free).
// Wave w owns output rows 2w, 2w+1 -> acc[4][2].
// MODE 0: chunks 0-15 = W on AM (G=acc+biases stored at k==15), 16-31 = U on
//         H0; LSTM with c_src=x.  MODE 1: z=acc+G; LSTM; c,h out.  MODE 2:
//         final: write d_out (NCHW f32).
// ---------------------------------------------------------------------------
template <int MODE>
__launch_bounds__(512, 2)
__global__ void conv4(const u16* __restrict__ inA, const u16* __restrict__ inH,
                      const u16* __restrict__ wW, const u16* __restrict__ wU,
                      const float* __restrict__ bWi, const float* __restrict__ bUi,
                      const float* __restrict__ bWf, const float* __restrict__ bUf,
                      const float* __restrict__ bWo, const float* __restrict__ bUo,
                      const float* __restrict__ bWc, const float* __restrict__ bUc,
                      float* __restrict__ G, const float* __restrict__ c_src,
                      float* __restrict__ c_dst, u16* __restrict__ h_out,
                      float* __restrict__ out) {
  __shared__ __align__(16) u16 Alds[2][9 * 4 * 64 * 8];  // [k9][gate][lane][8] 2x36864 B
  __shared__ __align__(16) u16 Blds[2][18 * 18 * 32];    // [r 18][xx 18][slot 4][8] 2x20736 B
  const int tid = threadIdx.x;
  const int chgrp = blockIdx.x & 31;
  const int b = blockIdx.x >> 5;
  const int wave = tid >> 6, lane = tid & 63;
  const int row = lane & 15, quad = lane >> 4;
  const int NCH = (MODE == 0) ? 32 : 16;

  // Zero both B buffers once (borders persist; DMA overwrites interior only).
  {
    i32x4 z = {0, 0, 0, 0};
    i32x4* bz = (i32x4*)&Blds[0][0];
#pragma unroll
    for (int i = 0; i < 6; ++i) {
      int k = tid + 512 * i;
      if (k < 2592) bz[k] = z;
    }
  }
  __syncthreads();  // zeroing must complete before stage(0)'s DMA lands

  const u16* wsrcW = wW + (size_t)chgrp * 294912;
  const u16* wsrcU = wU + (size_t)chgrp * 294912;
  const u16* isrcA = inA + (size_t)b * 131072;
  const u16* isrcH = inH + (size_t)b * 131072;

  auto stage = [&](int k, int bb) {
    const u16* gw;
    const u16* gi;
    if (MODE == 0 && k < 16) { gw = wsrcW + k * 18432; gi = isrcA + k * 32; }
    else                     { gw = wsrcU + (k & 15) * 18432; gi = isrcH + (k & 15) * 32; }
    // weights: 36 KB = 36 wave-level 1KB DMAs, linear fragment-major copy
    u16* Ab = &Alds[bb][0];
#pragma unroll
    for (int i = 0; i < 5; ++i) {
      int idx = i * 8 + wave;
      if (idx < 36) gl16(gw + (idx * 64 + lane) * 8, &Ab[idx * 512]);
    }
    // input rows: Blds row r = gy+1, gy in 0..15 (always interior, no branch).
    // Source channel-group XOR-pre-swizzled so the ds_read side can unswizzle.
    u16* Bb = &Blds[bb][0];
    int xi = lane >> 2;
    int qsrc = (lane & 3) ^ (((xi + 1) >> 2) & 3);
#pragma unroll
    for (int j = 0; j < 2; ++j) {
      int gy = wave + j * 8;
      gl16(gi + (size_t)(gy * 16 + xi) * 512 + qsrc * 8, &Bb[(gy + 1) * 576 + 32]);
    }
  };

  f32x4 acc[4][2];
#pragma unroll
  for (int m = 0; m < 4; ++m)
#pragma unroll
    for (int n = 0; n < 2; ++n) acc[m][n] = (f32x4){0.f, 0.f, 0.f, 0.f};

  const int ch0 = chgrp * 16 + quad * 4;
  float* gptr = G + (size_t)blockIdx.x * 16384 + wave * 2048 + lane * 4;

  stage(0, 0);
  __syncthreads();  // drains DMA (vmcnt0) -> chunk 0 ready
  int bb = 0;

#pragma unroll 1
  for (int k = 0; k < NCH; ++k) {
    if (k + 1 < NCH) stage(k + 1, bb ^ 1);   // issue next-chunk DMA FIRST
    const u16* Ab = &Alds[bb][0];
    const u16* Bb = &Blds[bb][0];
#pragma unroll
    for (int kx = 0; kx < 3; ++kx) {
      int xx = row + kx;
      int qs = quad ^ ((xx >> 2) & 3);          // undo the DMA-side XOR
      f16x8 bfr[4];  // Blds rows wave*2 .. wave*2+3 (shared across ky,n)
#pragma unroll
      for (int jj = 0; jj < 4; ++jj)
        bfr[jj] = *(const f16x8*)(&Bb[(wave * 2 + jj) * 576 + xx * 32 + qs * 8]);
#pragma unroll
      for (int ky = 0; ky < 3; ++ky) {
#pragma unroll
        for (int m = 0; m < 4; ++m) {
          f16x8 af = *(const f16x8*)(&Ab[((ky * 3 + kx) * 4 + m) * 512 + lane * 8]);
#pragma unroll
          for (int n = 0; n < 2; ++n)
            acc[m][n] = __builtin_amdgcn_mfma_f32_16x16x32_f16(af, bfr[n + ky], acc[m][n], 0, 0, 0);
        }
      }
    }
    if constexpr (MODE == 0) {
      if (k == 15) {  // W-half done: add biases, persist G = conv(AM,W)+bW+bU
#pragma unroll
        for (int m = 0; m < 4; ++m) {
          const float* bw = m == 0 ? bWi : m == 1 ? bWf : m == 2 ? bWo : bWc;
          const float* bu = m == 0 ? bUi : m == 1 ? bUf : m == 2 ? bUo : bUc;
          f32x4 bias;
#pragma unroll
          for (int r = 0; r < 4; ++r) bias[r] = bw[ch0 + r] + bu[ch0 + r];
#pragma unroll
          for (int n = 0; n < 2; ++n) {
            acc[m][n] = acc[m][n] + bias;
            *(f32x4*)(gptr + (m * 2 + n) * 256) = acc[m][n];
          }
        }
      }
    }
    __syncthreads();  // waves done reading bb; DMA into bb^1 drained (vmcnt0)
    bb ^= 1;
  }

  // ---- epilogue: LSTM update ----
#pragma unroll
  for (int n = 0; n < 2; ++n) {
    const int p = (wave * 2 + n) * 16 + row;
    f32x4 zi = acc[0][n], zf = acc[1][n], zo = acc[2][n], zg = acc[3][n];
    if constexpr (MODE != 0) {
      zi = zi + *(const f32x4*)(gptr + (0 + n) * 256);
      zf = zf + *(const f32x4*)(gptr + (2 + n) * 256);
      zo = zo + *(const f32x4*)(gptr + (4 + n) * 256);
      zg = zg + *(const f32x4*)(gptr + (6 + n) * 256);
    }
    f32x4 cold;
#pragma unroll
    for (int r = 0; r < 4; ++r)
      cold[r] = c_src[(size_t)(b * 512 + ch0 + r) * 256 + p];
    f32x4 cnew, hv;
#pragma unroll
    for (int r = 0; r < 4; ++r) {
      float iv = sigm(zi[r]);
      float fv = sigm(zf[r]);
      float ov = sigm(zo[r]);
      float gv = tanh_(zg[r]);
      float cn = fmaf(gv, iv, fv * cold[r]);
      cnew[r] = cn;
      hv[r] = tanh_(cn) * ov;
    }
    if constexpr (MODE != 2) {
#pragma unroll
      for (int r = 0; r < 4; ++r)
        c_dst[(size_t)(b * 512 + ch0 + r) * 256 + p] = cnew[r];
      us4 hb;
      hb[0] = f2h(hv[0]); hb[1] = f2h(hv[1]);
      hb[2] = f2h(hv[2]); hb[3] = f2h(hv[3]);
      *(us4*)(h_out + (size_t)b * 131072 + (size_t)p * 512 + ch0) = hb;
    } else {
#pragma unroll
      for (int r = 0; r < 4; ++r)
        out[(size_t)(b * 512 + ch0 + r) * 256 + p] = hv[r];
    }
  }
}

extern "C" void kernel_launch(void* const* d_in, const int* in_sizes, int n_in,
                              void* d_out, int out_size, void* d_ws, size_t ws_size,
                              hipStream_t stream) {
  const float* x    = (const float*)d_in[0];
  const float* txt  = (const float*)d_in[1];
  const float* Wi_w = (const float*)d_in[7];
  const float* Wi_b = (const float*)d_in[8];
  const float* Ui_w = (const float*)d_in[9];
  const float* Ui_b = (const float*)d_in[10];
  const float* Wf_w = (const float*)d_in[11];
  const float* Wf_b = (const float*)d_in[12];
  const float* Uf_w = (const float*)d_in[13];
  const float* Uf_b = (const float*)d_in[14];
  const float* Wc_w = (const float*)d_in[15];
  const float* Wc_b = (const float*)d_in[16];
  const float* Uc_w = (const float*)d_in[17];
  const float* Uc_b = (const float*)d_in[18];
  const float* Wo_w = (const float*)d_in[19];
  const float* Wo_b = (const float*)d_in[20];
  const float* Uo_w = (const float*)d_in[21];
  const float* Uo_b = (const float*)d_in[22];
  const float* WQ   = (const float*)d_in[23];
  const float* WK   = (const float*)d_in[24];
  const float* WV   = (const float*)d_in[25];
  const float* Wsw  = (const float*)d_in[26];
  const float* Wsb  = (const float*)d_in[27];
  (void)in_sizes; (void)n_in; (void)ws_size;

  char* ws = (char*)d_ws;
  size_t off = 0;
  auto carve = [&](size_t n) {
    char* p = ws + off;
    off += (n + 255) & ~(size_t)255;
    return p;
  };
  u16* WswzW    = (u16*)carve(18874368);   // 4x512x512x9 fp16, fragment-major
  u16* WswzU    = (u16*)carve(18874368);
  u16* AM       = (u16*)carve(2097152);    // fp16 NHWC
  u16* H0       = (u16*)carve(2097152);
  u16* H1       = (u16*)carve(2097152);
  float* G      = (float*)carve(16777216); // fragment-layout W-conv + biases
  float* C      = (float*)carve(4194304);  // cell state, NCHW f32
  float* scores = (float*)carve(8192);     // [8 b][256 p]
  float* sb     = (float*)carve(256);      // s, b0

  hipMemsetAsync(scores, 0, 8192, stream);  // scores accumulated via atomicAdd

  prep_big<<<3072, 256, 0, stream>>>(WQ, WK, txt, WV, Wsw, Wsb,
                                     Wi_w, Wf_w, Wo_w, Wc_w,
                                     Ui_w, Uf_w, Uo_w, Uc_w,
                                     WswzW, WswzU, scores, sb);
  prep_inputs<<<4096, 256, 0, stream>>>(x, scores, sb, AM, H0);

  // t=0 fused (W on AM + U on H0), then 3 more timesteps ping-ponging h.
  conv4<0><<<256, 512, 0, stream>>>(AM, H0, WswzW, WswzU,
                                    Wi_b, Ui_b, Wf_b, Uf_b, Wo_b, Uo_b, Wc_b, Uc_b,
                                    G, x, C, H1, nullptr);
  conv4<1><<<256, 512, 0, stream>>>(nullptr, H1, nullptr, WswzU,
                                    nullptr, nullptr, nullptr, nullptr,
                                    nullptr, nullptr, nullptr, nullptr,
                                    G, C, C, H0, nullptr);
  conv4<1><<<256, 512, 0, stream>>>(nullptr, H0, nullptr, WswzU,
                                    nullptr, nullptr, nullptr, nullptr,
                                    nullptr, nullptr, nullptr, nullptr,
                                    G, C, C, H1, nullptr);
  conv4<2><<<256, 512, 0, stream>>>(nullptr, H1, nullptr, WswzU,
                                    nullptr, nullptr, nullptr, nullptr,
                                    nullptr, nullptr, nullptr, nullptr,
                                    G, C, nullptr, nullptr, (float*)d_out);
}

// Round 3
// 508.193 us; speedup vs baseline: 1.0158x; 1.0158x over previous
//
#include <hip/hip_runtime.h>

typedef unsigned short u16;
typedef __attribute__((ext_vector_type(8))) _Float16 f16x8;
typedef __attribute__((ext_vector_type(4))) float f32x4;
typedef __attribute__((ext_vector_type(4))) int i32x4;
typedef __attribute__((ext_vector_type(4))) unsigned short us4;

__device__ __forceinline__ u16 f2h(float f) {
  _Float16 h = (_Float16)f;
  return __builtin_bit_cast(unsigned short, h);
}
__device__ __forceinline__ float sigm(float v) { return 1.0f / (1.0f + __expf(-v)); }
__device__ __forceinline__ float tanh_(float v) {
  float t = __expf(-2.0f * fabsf(v));
  float r = (1.0f - t) / (1.0f + t);
  return v >= 0.0f ? r : -r;
}

// async global->LDS DMA, 16 B per lane; LDS dest = wave-uniform base + lane*16
typedef const __attribute__((address_space(1))) unsigned int* gas_t;
typedef __attribute__((address_space(3))) unsigned int* las_t;
__device__ __forceinline__ void gl16(const u16* g, u16* l) {
  __builtin_amdgcn_global_load_lds((gas_t)g, (las_t)l, 16, 0, 0);
}

// ---------------------------------------------------------------------------
// prep_scores: [es 8][p 256] blocks. scores[b][p] += (sum_e-slice WQ*WK)·txt.
// All 20 loads (16 WQ f32x4 + 4 WK) issued before any FMA via sched_barrier.
// Block 0 also computes sb.
// ---------------------------------------------------------------------------
__global__ __launch_bounds__(256, 4) void prep_scores(
    const float* __restrict__ WQ, const float* __restrict__ WK,
    const float* __restrict__ txt, const float* __restrict__ WV,
    const float* __restrict__ Wsw, const float* __restrict__ Wsb,
    float* __restrict__ scores, float* __restrict__ sb) {
  __shared__ float red[4][8];
  __shared__ float red2[4];
  int tid = threadIdx.x;
  int p = blockIdx.x & 255;
  int es = blockIdx.x >> 8;                    // e-slice 0..7
  int t4 = tid & 63, eg = tid >> 6;            // t = t4*4..+3, e-subgroup eg
  const f32x4* base = (const f32x4*)WQ + ((size_t)p * 512 + es * 64 + eg * 16) * 64 + t4;
  f32x4 va[16];                                // 16 independent 16B loads in flight
#pragma unroll
  for (int i = 0; i < 16; ++i) va[i] = base[i * 64];
  f32x4 wkq[4];
  const f32x4* wkp = (const f32x4*)(WK + es * 64 + eg * 16);
#pragma unroll
  for (int i = 0; i < 4; ++i) wkq[i] = wkp[i];
  __builtin_amdgcn_sched_barrier(0);           // pin: all 20 loads issue first
  f32x4 m4 = {0.f, 0.f, 0.f, 0.f};
#pragma unroll
  for (int i = 0; i < 4; ++i)
#pragma unroll
    for (int e = 0; e < 4; ++e) m4 += va[i * 4 + e] * wkq[i][e];
  // all 8 batches at once: ILP across the shuffle chains, single barrier
  float v[8];
  const f32x4* txp = (const f32x4*)txt;
#pragma unroll
  for (int b = 0; b < 8; ++b) {
    f32x4 tx = txp[b * 64 + t4];
    v[b] = m4[0] * tx[0] + m4[1] * tx[1] + m4[2] * tx[2] + m4[3] * tx[3];
  }
#pragma unroll
  for (int off = 32; off; off >>= 1)
#pragma unroll
    for (int b = 0; b < 8; ++b) v[b] += __shfl_down(v[b], off, 64);
  if (t4 == 0)
#pragma unroll
    for (int b = 0; b < 8; ++b) red[eg][b] = v[b];
  __syncthreads();
  if (tid < 8) {
    float sv = red[0][tid] + red[1][tid] + red[2][tid] + red[3][tid];
    atomicAdd(&scores[tid * 256 + p], sv * 0.044194173824159216f);
  }
  if (blockIdx.x == 0) {
    float vv = WV[tid] * Wsw[tid] + WV[tid + 256] * Wsw[tid + 256];
#pragma unroll
    for (int off = 32; off; off >>= 1) vv += __shfl_down(vv, off, 64);
    if (t4 == 0) red2[eg] = vv;
    __syncthreads();
    if (tid == 0) {
      sb[0] = red2[0] + red2[1] + red2[2] + red2[3];
      sb[1] = Wsb[0];
    }
  }
}

// ---------------------------------------------------------------------------
// prep_swz: [set 2][chgrp 32][chunk 16] weight swizzle, LDS-free,
// fragment-major output: u16 idx = ((k9*4+gate)*64 + q*16+chrow)*8 + c8
// so conv4's A ds_read_b128 is linear lane*16 (0 conflicts).
// ---------------------------------------------------------------------------
__global__ __launch_bounds__(256, 4) void prep_swz(
    const float* __restrict__ wi, const float* __restrict__ wf,
    const float* __restrict__ wo, const float* __restrict__ wc,
    const float* __restrict__ ui, const float* __restrict__ uf,
    const float* __restrict__ uo, const float* __restrict__ uc,
    u16* __restrict__ dstW, u16* __restrict__ dstU) {
  int tid = threadIdx.x;
  int sbid = blockIdx.x;                       // 0..1023
  int set = sbid >> 9;
  int chgrp = (sbid >> 4) & 31;
  int chunk = sbid & 15;
  int q = tid & 3, gch = tid >> 2;             // 4 threads per (gate,chrow)
  int gate = gch >> 4, chrow = gch & 15;
  int ch = chgrp * 16 + chrow;
  const float* s;
  if (set == 0) s = gate == 0 ? wi : gate == 1 ? wf : gate == 2 ? wo : wc;
  else          s = gate == 0 ? ui : gate == 1 ? uf : gate == 2 ? uo : uc;
  // this thread's 72 contiguous floats: [cl = q*8 .. q*8+7][k9 0..8]
  const f32x4* src = (const f32x4*)(s + (size_t)(ch * 512 + chunk * 32) * 9) + q * 18;
  f32x4 va[18];
#pragma unroll
  for (int i = 0; i < 18; ++i) va[i] = src[i];
  __builtin_amdgcn_sched_barrier(0);           // pin: all 18 loads issue first
  u16* dst = (set == 0 ? dstW : dstU) + (size_t)(chgrp * 16 + chunk) * 18432
             + (size_t)(gate * 64 + q * 16 + chrow) * 8;
#pragma unroll
  for (int k9 = 0; k9 < 9; ++k9) {
    i32x4 wv;
#pragma unroll
    for (int w = 0; w < 4; ++w) {
      int i0 = (2 * w) * 9 + k9, i1 = (2 * w + 1) * 9 + k9;
      unsigned lo = f2h(va[i0 >> 2][i0 & 3]);
      unsigned hi = f2h(va[i1 >> 2][i1 & 3]);
      wv[w] = (int)(lo | (hi << 16));
    }
    *(i32x4*)(dst + k9 * 2048) = wv;           // wave covers a full 1KB line set
  }
}

// ---------------------------------------------------------------------------
// prep_inputs: coef from scores (softmax over h per (b,w)); AM = coef*x,
// H0 = x, fp16 NHWC [b][p][ch].
// ---------------------------------------------------------------------------
__global__ void prep_inputs(const float* __restrict__ x, const float* __restrict__ scores,
                            const float* __restrict__ sb,
                            u16* __restrict__ AM, u16* __restrict__ H0) {
  __shared__ float sc[16];
  int idx = blockIdx.x * 256 + threadIdx.x;  // NHWC flat index
  int ch = idx & 511, p = (idx >> 9) & 255, b = idx >> 17;
  int w = p & 15, h = p >> 4;
  if (threadIdx.x < 16) sc[threadIdx.x] = scores[b * 256 + threadIdx.x * 16 + w];
  __syncthreads();
  float s = sb[0], b0 = sb[1];
  float mx = -1e30f;
#pragma unroll
  for (int hh = 0; hh < 16; ++hh) mx = fmaxf(mx, sc[hh]);
  float den = 0.f, my = 0.f;
#pragma unroll
  for (int hh = 0; hh < 16; ++hh) {
    float e = __expf(sc[hh] - mx);
    den += e;
    if (hh == h) my = e;
  }
  float coef = 1.0f + b0 + s * my / den;
  float xv = x[(size_t)(b * 512 + ch) * 256 + p];
  AM[idx] = f2h(coef * xv);
  H0[idx] = f2h(xv);
}

// ---------------------------------------------------------------------------
// Fused 4-gate 3x3 conv, implicit GEMM (fp16 MFMA 16x16x32, fp32 acc).
// Grid 256 = [b 8][chgrp 32], 512 threads (8 waves), N=256 full image.
// RETILE this round: wave (mw = wave>>2, nw = wave&3) owns 2 gates
// {2mw,2mw+1} x 4 image rows {4nw..4nw+3} -> acc[2][4]. Per chunk per wave:
// 18 A-reads + 18 B-reads feed 72 MFMAs (was 36+12 for 72 -> A-traffic
// halves; each A-frag read feeds 4 MFMAs). All 12 reads per kx batched
// before the 24 MFMAs. Epilogue: one-time LDS exchange (mw=1 -> mw=0 waves)
// to reunite the 4 gates, reusing dead Blds.
// Double-buffered LDS (115KB, 1 block/CU), stage(k+1)-before-compute(k),
// one barrier per chunk. A fragment-major (linear lane*16, 0 conflicts);
// B XOR-swizzled at the DMA global source, undone at ds_read.
// MODE 0: chunks 0-15 = W on AM (G=acc+biases stored at k==15), 16-31 = U on
//         H0; LSTM c_src=x.  MODE 1: z=acc+G; LSTM; c,h out.  MODE 2: d_out.
// ---------------------------------------------------------------------------
template <int MODE>
__launch_bounds__(512, 2)
__global__ void conv4(const u16* __restrict__ inA, const u16* __restrict__ inH,
                      const u16* __restrict__ wW, const u16* __restrict__ wU,
                      const float* __restrict__ bWi, const float* __restrict__ bUi,
                      const float* __restrict__ bWf, const float* __restrict__ bUf,
                      const float* __restrict__ bWo, const float* __restrict__ bUo,
                      const float* __restrict__ bWc, const float* __restrict__ bUc,
                      float* __restrict__ G, const float* __restrict__ c_src,
                      float* __restrict__ c_dst, u16* __restrict__ h_out,
                      float* __restrict__ out) {
  __shared__ __align__(16) u16 Alds[2][9 * 4 * 64 * 8];  // [k9][gate][lane][8] 2x36864 B
  __shared__ __align__(16) u16 Blds[2][18 * 18 * 32];    // [r 18][xx 18][slot 4][8] 2x20736 B
  const int tid = threadIdx.x;
  const int chgrp = blockIdx.x & 31;
  const int b = blockIdx.x >> 5;
  const int wave = tid >> 6, lane = tid & 63;
  const int row = lane & 15, quad = lane >> 4;
  const int nw = wave & 3, mw = wave >> 2;
  const int NCH = (MODE == 0) ? 32 : 16;

  // Zero both B buffers once (borders persist; DMA overwrites interior only).
  {
    i32x4 z = {0, 0, 0, 0};
    i32x4* bz = (i32x4*)&Blds[0][0];
#pragma unroll
    for (int i = 0; i < 6; ++i) {
      int k = tid + 512 * i;
      if (k < 2592) bz[k] = z;
    }
  }
  __syncthreads();  // zeroing must complete before stage(0)'s DMA lands

  const u16* wsrcW = wW + (size_t)chgrp * 294912;
  const u16* wsrcU = wU + (size_t)chgrp * 294912;
  const u16* isrcA = inA + (size_t)b * 131072;
  const u16* isrcH = inH + (size_t)b * 131072;

  auto stage = [&](int k, int bb) {
    const u16* gw;
    const u16* gi;
    if (MODE == 0 && k < 16) { gw = wsrcW + k * 18432; gi = isrcA + k * 32; }
    else                     { gw = wsrcU + (k & 15) * 18432; gi = isrcH + (k & 15) * 32; }
    // weights: 36 KB = 36 wave-level 1KB DMAs, linear fragment-major copy
    u16* Ab = &Alds[bb][0];
#pragma unroll
    for (int i = 0; i < 5; ++i) {
      int idx = i * 8 + wave;
      if (idx < 36) gl16(gw + (idx * 64 + lane) * 8, &Ab[idx * 512]);
    }
    // input rows: Blds row gy+1 <- global row gy (interior only).
    // Source channel-group XOR-pre-swizzled so the ds_read side can unswizzle.
    u16* Bb = &Blds[bb][0];
    int xi = lane >> 2;
    int qsrc = (lane & 3) ^ (((xi + 1) >> 2) & 3);
#pragma unroll
    for (int j = 0; j < 2; ++j) {
      int gy = wave + j * 8;
      gl16(gi + (size_t)(gy * 16 + xi) * 512 + qsrc * 8, &Bb[(gy + 1) * 576 + 32]);
    }
  };

  f32x4 acc[2][4];  // [m gate-pair][jj row]
#pragma unroll
  for (int m = 0; m < 2; ++m)
#pragma unroll
    for (int jj = 0; jj < 4; ++jj) acc[m][jj] = (f32x4){0.f, 0.f, 0.f, 0.f};

  const int ch0 = chgrp * 16 + quad * 4;
  float* gptr = G + (size_t)blockIdx.x * 16384 + wave * 2048 + lane * 4;

  stage(0, 0);
  __syncthreads();  // drains DMA (vmcnt0) -> chunk 0 ready
  int bb = 0;

#pragma unroll 1
  for (int k = 0; k < NCH; ++k) {
    if (k + 1 < NCH) stage(k + 1, bb ^ 1);   // issue next-chunk DMA FIRST
    const u16* Ab = &Alds[bb][0];
    const u16* Bb = &Blds[bb][0];
#pragma unroll
    for (int kx = 0; kx < 3; ++kx) {
      int xx = row + kx;
      int qs = quad ^ ((xx >> 2) & 3);          // undo the DMA-side XOR
      f16x8 bfr[6];                             // image rows 4nw-1..4nw+4
#pragma unroll
      for (int rr = 0; rr < 6; ++rr)
        bfr[rr] = *(const f16x8*)(&Bb[(4 * nw + rr) * 576 + xx * 32 + qs * 8]);
      f16x8 afr[6];                             // (ky 0..2) x (m 0..1) at this kx
#pragma unroll
      for (int ky = 0; ky < 3; ++ky)
#pragma unroll
        for (int m = 0; m < 2; ++m)
          afr[ky * 2 + m] = *(const f16x8*)(&Ab[((ky * 3 + kx) * 4 + 2 * mw + m) * 512 + lane * 8]);
#pragma unroll
      for (int ky = 0; ky < 3; ++ky)
#pragma unroll
        for (int m = 0; m < 2; ++m)
#pragma unroll
          for (int jj = 0; jj < 4; ++jj)
            acc[m][jj] = __builtin_amdgcn_mfma_f32_16x16x32_f16(afr[ky * 2 + m], bfr[jj + ky],
                                                                acc[m][jj], 0, 0, 0);
    }
    if constexpr (MODE == 0) {
      if (k == 15) {  // W-half done: add biases, persist G = conv(AM,W)+bW+bU
#pragma unroll
        for (int m = 0; m < 2; ++m) {
          int g = 2 * mw + m;
          const float* bw = g == 0 ? bWi : g == 1 ? bWf : g == 2 ? bWo : bWc;
          const float* bu = g == 0 ? bUi : g == 1 ? bUf : g == 2 ? bUo : bUc;
          f32x4 bias;
#pragma unroll
          for (int r = 0; r < 4; ++r) bias[r] = bw[ch0 + r] + bu[ch0 + r];
#pragma unroll
          for (int jj = 0; jj < 4; ++jj) {
            acc[m][jj] = acc[m][jj] + bias;
            *(f32x4*)(gptr + (m * 4 + jj) * 256) = acc[m][jj];
          }
        }
      }
    }
    __syncthreads();  // waves done reading bb; DMA into bb^1 drained (vmcnt0)
    bb ^= 1;
  }

  // ---- epilogue: reunite gates, LSTM update ----
  if constexpr (MODE != 0) {
#pragma unroll
    for (int m = 0; m < 2; ++m)
#pragma unroll
      for (int jj = 0; jj < 4; ++jj)
        acc[m][jj] = acc[m][jj] + *(const f32x4*)(gptr + (m * 4 + jj) * 256);
  }
  float* X = (float*)&Blds[0][0];  // 32KB exchange buffer (Blds is dead, 41.4KB)
  if (mw == 1) {
#pragma unroll
    for (int m = 0; m < 2; ++m)
#pragma unroll
      for (int jj = 0; jj < 4; ++jj)
        *(f32x4*)(X + (size_t)(((nw * 2 + m) * 4 + jj) * 256) + lane * 4) = acc[m][jj];
  }
  __syncthreads();
  if (mw == 0) {
#pragma unroll
    for (int jj = 0; jj < 4; ++jj) {
      const int p = (4 * nw + jj) * 16 + row;
      f32x4 zi = acc[0][jj], zf = acc[1][jj];
      f32x4 zo = *(const f32x4*)(X + (size_t)(((nw * 2 + 0) * 4 + jj) * 256) + lane * 4);
      f32x4 zg = *(const f32x4*)(X + (size_t)(((nw * 2 + 1) * 4 + jj) * 256) + lane * 4);
      f32x4 cold;
#pragma unroll
      for (int r = 0; r < 4; ++r)
        cold[r] = c_src[(size_t)(b * 512 + ch0 + r) * 256 + p];
      f32x4 cnew, hv;
#pragma unroll
      for (int r = 0; r < 4; ++r) {
        float iv = sigm(zi[r]);
        float fv = sigm(zf[r]);
        float ov = sigm(zo[r]);
        float gv = tanh_(zg[r]);
        float cn = fmaf(gv, iv, fv * cold[r]);
        cnew[r] = cn;
        hv[r] = tanh_(cn) * ov;
      }
      if constexpr (MODE != 2) {
#pragma unroll
        for (int r = 0; r < 4; ++r)
          c_dst[(size_t)(b * 512 + ch0 + r) * 256 + p] = cnew[r];
        us4 hb;
        hb[0] = f2h(hv[0]); hb[1] = f2h(hv[1]);
        hb[2] = f2h(hv[2]); hb[3] = f2h(hv[3]);
        *(us4*)(h_out + (size_t)b * 131072 + (size_t)p * 512 + ch0) = hb;
      } else {
#pragma unroll
        for (int r = 0; r < 4; ++r)
          out[(size_t)(b * 512 + ch0 + r) * 256 + p] = hv[r];
      }
    }
  }
}

extern "C" void kernel_launch(void* const* d_in, const int* in_sizes, int n_in,
                              void* d_out, int out_size, void* d_ws, size_t ws_size,
                              hipStream_t stream) {
  const float* x    = (const float*)d_in[0];
  const float* txt  = (const float*)d_in[1];
  const float* Wi_w = (const float*)d_in[7];
  const float* Wi_b = (const float*)d_in[8];
  const float* Ui_w = (const float*)d_in[9];
  const float* Ui_b = (const float*)d_in[10];
  const float* Wf_w = (const float*)d_in[11];
  const float* Wf_b = (const float*)d_in[12];
  const float* Uf_w = (const float*)d_in[13];
  const float* Uf_b = (const float*)d_in[14];
  const float* Wc_w = (const float*)d_in[15];
  const float* Wc_b = (const float*)d_in[16];
  const float* Uc_w = (const float*)d_in[17];
  const float* Uc_b = (const float*)d_in[18];
  const float* Wo_w = (const float*)d_in[19];
  const float* Wo_b = (const float*)d_in[20];
  const float* Uo_w = (const float*)d_in[21];
  const float* Uo_b = (const float*)d_in[22];
  const float* WQ   = (const float*)d_in[23];
  const float* WK   = (const float*)d_in[24];
  const float* WV   = (const float*)d_in[25];
  const float* Wsw  = (const float*)d_in[26];
  const float* Wsb  = (const float*)d_in[27];
  (void)in_sizes; (void)n_in; (void)ws_size;

  char* ws = (char*)d_ws;
  size_t off = 0;
  auto carve = [&](size_t n) {
    char* p = ws + off;
    off += (n + 255) & ~(size_t)255;
    return p;
  };
  u16* WswzW    = (u16*)carve(18874368);   // 4x512x512x9 fp16, fragment-major
  u16* WswzU    = (u16*)carve(18874368);
  u16* AM       = (u16*)carve(2097152);    // fp16 NHWC
  u16* H0       = (u16*)carve(2097152);
  u16* H1       = (u16*)carve(2097152);
  float* G      = (float*)carve(16777216); // fragment-layout W-conv + biases
  float* C      = (float*)carve(4194304);  // cell state, NCHW f32
  float* scores = (float*)carve(8192);     // [8 b][256 p]
  float* sb     = (float*)carve(256);      // s, b0

  hipMemsetAsync(scores, 0, 8192, stream);  // scores accumulated via atomicAdd

  prep_scores<<<2048, 256, 0, stream>>>(WQ, WK, txt, WV, Wsw, Wsb, scores, sb);
  prep_swz<<<1024, 256, 0, stream>>>(Wi_w, Wf_w, Wo_w, Wc_w,
                                     Ui_w, Uf_w, Uo_w, Uc_w, WswzW, WswzU);
  prep_inputs<<<4096, 256, 0, stream>>>(x, scores, sb, AM, H0);

  // t=0 fused (W on AM + U on H0), then 3 more timesteps ping-ponging h.
  conv4<0><<<256, 512, 0, stream>>>(AM, H0, WswzW, WswzU,
                                    Wi_b, Ui_b, Wf_b, Uf_b, Wo_b, Uo_b, Wc_b, Uc_b,
                                    G, x, C, H1, nullptr);
  conv4<1><<<256, 512, 0, stream>>>(nullptr, H1, nullptr, WswzU,
                                    nullptr, nullptr, nullptr, nullptr,
                                    nullptr, nullptr, nullptr, nullptr,
                                    G, C, C, H0, nullptr);
  conv4<1><<<256, 512, 0, stream>>>(nullptr, H0, nullptr, WswzU,
                                    nullptr, nullptr, nullptr, nullptr,
                                    nullptr, nullptr, nullptr, nullptr,
                                    G, C, C, H1, nullptr);
  conv4<2><<<256, 512, 0, stream>>>(nullptr, H1, nullptr, WswzU,
                                    nullptr, nullptr, nullptr, nullptr,
                                    nullptr, nullptr, nullptr, nullptr,
                                    G, C, nullptr, nullptr, (float*)d_out);
}